// Round 2
// baseline (434.345 us; speedup 1.0000x reference)
//
#include <hip/hip_runtime.h>

#define N_TOK  1024
#define D_DIM  1024
#define M_FFN  4096

__device__ __forceinline__ float wave_reduce(float v) {
    #pragma unroll
    for (int off = 32; off > 0; off >>= 1) v += __shfl_xor(v, off);
    return v;
}

// ---------------- LayerNorm over 1024-elem rows, f32 -> f32 ---------------
__global__ void ln_kernel(const float* __restrict__ X,
                          const float* __restrict__ gam,
                          const float* __restrict__ bet,
                          float* __restrict__ Y) {
    int b = blockIdx.x, t = threadIdx.x;           // 256 threads, 4 elems each
    float4 x = ((const float4*)(X + (size_t)b * N_TOK))[t];
    float s = x.x + x.y + x.z + x.w;
    float q = x.x*x.x + x.y*x.y + x.z*x.z + x.w*x.w;
    s = wave_reduce(s); q = wave_reduce(q);
    __shared__ float sa[4], sb[4];
    int wid = t >> 6;
    if ((t & 63) == 0) { sa[wid] = s; sb[wid] = q; }
    __syncthreads();
    float ts = sa[0] + sa[1] + sa[2] + sa[3];
    float tq = sb[0] + sb[1] + sb[2] + sb[3];
    float mean = ts * (1.f / N_TOK);
    float var  = tq * (1.f / N_TOK) - mean * mean;
    float rs = rsqrtf(var + 1e-5f);
    float4 g4 = ((const float4*)gam)[t];
    float4 b4 = ((const float4*)bet)[t];
    float4 o;
    o.x = (x.x - mean) * rs * g4.x + b4.x;
    o.y = (x.y - mean) * rs * g4.y + b4.y;
    o.z = (x.z - mean) * rs * g4.z + b4.z;
    o.w = (x.w - mean) * rs * g4.w + b4.w;
    ((float4*)(Y + (size_t)b * N_TOK))[t] = o;
}

// ---- C(32 x N) += A(32 x K) @ W(N x K)^T, split-K, fp32 atomics ----------
// Grid: (N/64, K/kchunk), block 256. lane = output column (coalesced W),
// wave-uniform A reads (broadcast). 8 rows per thread.
__global__ void gemm_tn_kernel(const float* __restrict__ A,
                               const float* __restrict__ W,
                               float* __restrict__ Cacc,
                               int N, int K, int kchunk) {
    int t = threadIdx.x;
    int lane = t & 63;
    int wv = t >> 6;                               // 0..3
    int n = blockIdx.x * 64 + lane;
    int k0 = blockIdx.y * kchunk;
    const float* wp = W + (size_t)n * K + k0;
    const float* ap = A + k0;
    float acc[8] = {0.f,0.f,0.f,0.f,0.f,0.f,0.f,0.f};
    for (int k = 0; k < kchunk; k += 4) {
        float4 w4 = *(const float4*)(wp + k);
        #pragma unroll
        for (int j = 0; j < 8; j++) {
            int m = wv * 8 + j;
            float4 a4 = *(const float4*)(ap + (size_t)m * K + k);
            acc[j] += w4.x*a4.x + w4.y*a4.y + w4.z*a4.z + w4.w*a4.w;
        }
    }
    #pragma unroll
    for (int j = 0; j < 8; j++)
        atomicAdd(Cacc + (size_t)(wv * 8 + j) * N + n, acc[j]);
}

// ------------- Gaussian-kernel attention row sweep (the big one) ----------
// One 256-thread block per (b,i) row of D=1024 floats.
__global__ void attn_kernel(const float* __restrict__ Kp,
                            const float* __restrict__ Vp,
                            const float* __restrict__ Qp,
                            const float* __restrict__ mu_acc,
                            const float* __restrict__ sg_acc,
                            const float* __restrict__ mu_b,
                            const float* __restrict__ sg_b,
                            float* __restrict__ xo) {
    int row = blockIdx.x;                // b*1024 + i
    int i = row & (N_TOK - 1);
    int t = threadIdx.x;                 // 256
    float mu = tanhf(mu_acc[row] + mu_b[i]);
    float sg = sg_acc[row] + sg_b[i];
    float coef = -0.5f / (sg * sg + 1e-8f);
    size_t base = (size_t)row * D_DIM;
    float4 k4 = ((const float4*)(Kp + base))[t];
    float4 v4 = ((const float4*)(Vp + base))[t];
    float d, acc = 0.f;
    d = k4.x - mu; acc += __expf(coef * d * d) * v4.x;
    d = k4.y - mu; acc += __expf(coef * d * d) * v4.y;
    d = k4.z - mu; acc += __expf(coef * d * d) * v4.z;
    d = k4.w - mu; acc += __expf(coef * d * d) * v4.w;
    acc = wave_reduce(acc);
    __shared__ float sred[4];
    if ((t & 63) == 0) sred[t >> 6] = acc;
    __syncthreads();
    if (t == 0) xo[row] = sred[0] + sred[1] + sred[2] + sred[3] + Qp[row];
}

// --------------------- g = silu(acc + b1), f32 ----------------------------
__global__ void silu_kernel(const float* __restrict__ acc,
                            const float* __restrict__ b1,
                            float* __restrict__ g) {
    int idx = blockIdx.x * 256 + threadIdx.x;    // 131072 total
    float z = acc[idx] + b1[idx & (M_FFN - 1)];
    g[idx] = z / (1.f + __expf(-z));
}

// --------------------- out = x + acc2 + b2, f32 ---------------------------
__global__ void final_kernel(const float* __restrict__ x,
                             const float* __restrict__ acc2,
                             const float* __restrict__ b2,
                             float* __restrict__ out) {
    int idx = blockIdx.x * 256 + threadIdx.x;    // 32768 total
    out[idx] = x[idx] + acc2[idx] + b2[idx & (N_TOK - 1)];
}

extern "C" void kernel_launch(void* const* d_in, const int* in_sizes, int n_in,
                              void* d_out, int out_size, void* d_ws, size_t ws_size,
                              hipStream_t stream) {
    const float* Q       = (const float*)d_in[0];
    const float* Kp      = (const float*)d_in[1];
    const float* Vp      = (const float*)d_in[2];
    const float* mu_w    = (const float*)d_in[3];
    const float* mu_b    = (const float*)d_in[4];
    const float* sigma_w = (const float*)d_in[5];
    const float* sigma_b = (const float*)d_in[6];
    const float* w1      = (const float*)d_in[7];
    const float* b1      = (const float*)d_in[8];
    const float* w2      = (const float*)d_in[9];
    const float* b2      = (const float*)d_in[10];
    const float* ln_ff_g = (const float*)d_in[11];
    const float* ln_ff_b = (const float*)d_in[12];
    const float* ln_q_g  = (const float*)d_in[13];
    const float* ln_q_b  = (const float*)d_in[14];

    // Workspace layout (all fp32), ~1.82 MB total
    float* mu_acc = (float*)d_ws;                  // 32768
    float* sg_acc = mu_acc + 32768;                // 32768
    float* f1_acc = sg_acc + 32768;                // 131072
    float* f2_acc = f1_acc + 131072;               // 32768
    float* xbuf   = f2_acc + 32768;                // 32768 (fully written)
    float* qln    = xbuf   + 32768;                // 32768
    float* h0     = qln    + 32768;                // 32768
    float* g      = h0     + 32768;                // 131072

    // zero the atomic accumulators (mu, sigma, ffn1, ffn2) = 229376 floats
    hipMemsetAsync(mu_acc, 0, (size_t)229376 * sizeof(float), stream);

    // 1) q = LN(Q)
    ln_kernel<<<32, 256, 0, stream>>>(Q, ln_q_g, ln_q_b, qln);

    // 2) mu_acc = q @ mu_w^T ; sg_acc = q @ sigma_w^T  (bias/tanh fused into attn)
    gemm_tn_kernel<<<dim3(16, 8), 256, 0, stream>>>(qln, mu_w,    mu_acc, 1024, 1024, 128);
    gemm_tn_kernel<<<dim3(16, 8), 256, 0, stream>>>(qln, sigma_w, sg_acc, 1024, 1024, 128);

    // 3) x = sum_d exp(-0.5(K-mu)^2/(sigma^2+1e-8)) * V + Q
    attn_kernel<<<32 * N_TOK, 256, 0, stream>>>(Kp, Vp, Q, mu_acc, sg_acc,
                                                mu_b, sigma_b, xbuf);

    // 4) h0 = LN(x)
    ln_kernel<<<32, 256, 0, stream>>>(xbuf, ln_ff_g, ln_ff_b, h0);

    // 5) f1_acc = h0 @ w1^T ; g = silu(f1_acc + b1)
    gemm_tn_kernel<<<dim3(64, 4), 256, 0, stream>>>(h0, w1, f1_acc, 4096, 1024, 256);
    silu_kernel<<<512, 256, 0, stream>>>(f1_acc, b1, g);

    // 6) f2_acc = g @ w2^T ; out = x + f2_acc + b2
    gemm_tn_kernel<<<dim3(16, 8), 256, 0, stream>>>(g, w2, f2_acc, 1024, 4096, 512);
    final_kernel<<<128, 256, 0, stream>>>(xbuf, f2_acc, b2, (float*)d_out);
}

// Round 3
// 400.239 us; speedup vs baseline: 1.0852x; 1.0852x over previous
//
#include <hip/hip_runtime.h>

#define N_TOK  1024
#define D_DIM  1024
#define M_FFN  4096

__device__ __forceinline__ float wave_reduce(float v) {
    #pragma unroll
    for (int off = 32; off > 0; off >>= 1) v += __shfl_xor(v, off);
    return v;
}

// ---------------- LayerNorm over 1024-elem rows, f32 -> f32 ---------------
__global__ void ln_kernel(const float* __restrict__ X,
                          const float* __restrict__ gam,
                          const float* __restrict__ bet,
                          float* __restrict__ Y) {
    int b = blockIdx.x, t = threadIdx.x;           // 256 threads, 4 elems each
    float4 x = ((const float4*)(X + (size_t)b * N_TOK))[t];
    float s = x.x + x.y + x.z + x.w;
    float q = x.x*x.x + x.y*x.y + x.z*x.z + x.w*x.w;
    s = wave_reduce(s); q = wave_reduce(q);
    __shared__ float sa[4], sb[4];
    int wid = t >> 6;
    if ((t & 63) == 0) { sa[wid] = s; sb[wid] = q; }
    __syncthreads();
    float ts = sa[0] + sa[1] + sa[2] + sa[3];
    float tq = sb[0] + sb[1] + sb[2] + sb[3];
    float mean = ts * (1.f / N_TOK);
    float var  = tq * (1.f / N_TOK) - mean * mean;
    float rs = rsqrtf(var + 1e-5f);
    float4 g4 = ((const float4*)gam)[t];
    float4 b4 = ((const float4*)bet)[t];
    float4 o;
    o.x = (x.x - mean) * rs * g4.x + b4.x;
    o.y = (x.y - mean) * rs * g4.y + b4.y;
    o.z = (x.z - mean) * rs * g4.z + b4.z;
    o.w = (x.w - mean) * rs * g4.w + b4.w;
    ((float4*)(Y + (size_t)b * N_TOK))[t] = o;
}

// ---- C(32 x N) += A(32 x K) @ W(N x K)^T, split-K, fp32 atomics ----------
// Grid: (N/64, K/kchunk [, nmat]), block 256. lane = output column
// (coalesced W reads), wave-uniform A reads (broadcast). 8 rows per thread.
__global__ void gemm_tn_kernel(const float* __restrict__ A,
                               const float* __restrict__ W0,
                               const float* __restrict__ W1,
                               float* __restrict__ C0,
                               float* __restrict__ C1,
                               int N, int K, int kchunk) {
    int t = threadIdx.x;
    int lane = t & 63;
    int wv = t >> 6;                               // 0..3
    int n = blockIdx.x * 64 + lane;
    int k0 = blockIdx.y * kchunk;
    const float* W = blockIdx.z ? W1 : W0;
    float*      Cc = blockIdx.z ? C1 : C0;
    const float* wp = W + (size_t)n * K + k0;
    const float* ap = A + k0;
    float acc[8] = {0.f,0.f,0.f,0.f,0.f,0.f,0.f,0.f};
    for (int k = 0; k < kchunk; k += 4) {
        float4 w4 = *(const float4*)(wp + k);
        #pragma unroll
        for (int j = 0; j < 8; j++) {
            int m = wv * 8 + j;
            float4 a4 = *(const float4*)(ap + (size_t)m * K + k);
            acc[j] += w4.x*a4.x + w4.y*a4.y + w4.z*a4.z + w4.w*a4.w;
        }
    }
    #pragma unroll
    for (int j = 0; j < 8; j++)
        atomicAdd(Cc + (size_t)(wv * 8 + j) * N + n, acc[j]);
}

// ------------- Gaussian-kernel attention row sweep (the big one) ----------
// One WAVE per (b,i) row: 64 lanes x 16 elems = 1024. Block = 4 waves/rows.
// 8 independent 16B loads in flight per lane; no LDS, no __syncthreads.
__global__ void attn_kernel(const float* __restrict__ Kp,
                            const float* __restrict__ Vp,
                            const float* __restrict__ Qp,
                            const float* __restrict__ mu_acc,
                            const float* __restrict__ sg_acc,
                            const float* __restrict__ mu_b,
                            const float* __restrict__ sg_b,
                            float* __restrict__ xo) {
    int t = threadIdx.x;
    int row = blockIdx.x * 4 + (t >> 6);   // b*1024 + i
    int lane = t & 63;
    int i = row & (N_TOK - 1);
    const float4* kr = (const float4*)(Kp + (size_t)row * D_DIM);
    const float4* vr = (const float4*)(Vp + (size_t)row * D_DIM);
    float4 k4[4], v4[4];
    #pragma unroll
    for (int c = 0; c < 4; c++) k4[c] = kr[c * 64 + lane];
    #pragma unroll
    for (int c = 0; c < 4; c++) v4[c] = vr[c * 64 + lane];
    float mu = tanhf(mu_acc[row] + mu_b[i]);
    float sg = sg_acc[row] + sg_b[i];
    float coef = -0.5f / (sg * sg + 1e-8f);
    float acc = 0.f;
    #pragma unroll
    for (int c = 0; c < 4; c++) {
        float d;
        d = k4[c].x - mu; acc += __expf(coef * d * d) * v4[c].x;
        d = k4[c].y - mu; acc += __expf(coef * d * d) * v4[c].y;
        d = k4[c].z - mu; acc += __expf(coef * d * d) * v4[c].z;
        d = k4[c].w - mu; acc += __expf(coef * d * d) * v4[c].w;
    }
    acc = wave_reduce(acc);
    if (lane == 0) xo[row] = acc + Qp[row];
}

// --------------------- g = silu(acc + b1), f32 ----------------------------
__global__ void silu_kernel(const float* __restrict__ acc,
                            const float* __restrict__ b1,
                            float* __restrict__ g) {
    int idx = blockIdx.x * 256 + threadIdx.x;    // 131072 total
    float z = acc[idx] + b1[idx & (M_FFN - 1)];
    g[idx] = z / (1.f + __expf(-z));
}

// --------------------- out = x + acc2 + b2, f32 ---------------------------
__global__ void final_kernel(const float* __restrict__ x,
                             const float* __restrict__ acc2,
                             const float* __restrict__ b2,
                             float* __restrict__ out) {
    int idx = blockIdx.x * 256 + threadIdx.x;    // 32768 total
    out[idx] = x[idx] + acc2[idx] + b2[idx & (N_TOK - 1)];
}

extern "C" void kernel_launch(void* const* d_in, const int* in_sizes, int n_in,
                              void* d_out, int out_size, void* d_ws, size_t ws_size,
                              hipStream_t stream) {
    const float* Q       = (const float*)d_in[0];
    const float* Kp      = (const float*)d_in[1];
    const float* Vp      = (const float*)d_in[2];
    const float* mu_w    = (const float*)d_in[3];
    const float* mu_b    = (const float*)d_in[4];
    const float* sigma_w = (const float*)d_in[5];
    const float* sigma_b = (const float*)d_in[6];
    const float* w1      = (const float*)d_in[7];
    const float* b1      = (const float*)d_in[8];
    const float* w2      = (const float*)d_in[9];
    const float* b2      = (const float*)d_in[10];
    const float* ln_ff_g = (const float*)d_in[11];
    const float* ln_ff_b = (const float*)d_in[12];
    const float* ln_q_g  = (const float*)d_in[13];
    const float* ln_q_b  = (const float*)d_in[14];

    // Workspace layout (all fp32), ~1.82 MB total
    float* mu_acc = (float*)d_ws;                  // 32768
    float* sg_acc = mu_acc + 32768;                // 32768
    float* f1_acc = sg_acc + 32768;                // 131072
    float* f2_acc = f1_acc + 131072;               // 32768
    float* xbuf   = f2_acc + 32768;                // 32768 (fully written)
    float* qln    = xbuf   + 32768;                // 32768
    float* h0     = qln    + 32768;                // 32768
    float* g      = h0     + 32768;                // 131072

    // zero the atomic accumulators (mu, sigma, ffn1, ffn2) = 229376 floats
    hipMemsetAsync(mu_acc, 0, (size_t)229376 * sizeof(float), stream);

    // 1) q = LN(Q)
    ln_kernel<<<32, 256, 0, stream>>>(Q, ln_q_g, ln_q_b, qln);

    // 2) mu_acc = q @ mu_w^T ; sg_acc = q @ sigma_w^T  (one fused launch,
    //    blockIdx.z selects matrix; bias/tanh fused into attn)
    gemm_tn_kernel<<<dim3(16, 16, 2), 256, 0, stream>>>(
        qln, mu_w, sigma_w, mu_acc, sg_acc, 1024, 1024, 64);

    // 3) x = sum_d exp(-0.5(K-mu)^2/(sigma^2+1e-8)) * V + Q
    attn_kernel<<<8192, 256, 0, stream>>>(Kp, Vp, Q, mu_acc, sg_acc,
                                          mu_b, sigma_b, xbuf);

    // 4) h0 = LN(x)
    ln_kernel<<<32, 256, 0, stream>>>(xbuf, ln_ff_g, ln_ff_b, h0);

    // 5) f1_acc = h0 @ w1^T ; g = silu(f1_acc + b1)
    gemm_tn_kernel<<<dim3(64, 8, 1), 256, 0, stream>>>(
        h0, w1, w1, f1_acc, f1_acc, 4096, 1024, 128);
    silu_kernel<<<512, 256, 0, stream>>>(f1_acc, b1, g);

    // 6) f2_acc = g @ w2^T ; out = x + f2_acc + b2
    gemm_tn_kernel<<<dim3(16, 16, 1), 256, 0, stream>>>(
        g, w2, w2, f2_acc, f2_acc, 1024, 4096, 256);
    final_kernel<<<128, 256, 0, stream>>>(xbuf, f2_acc, b2, (float*)d_out);
}